// Round 2
// baseline (2919.751 us; speedup 1.0000x reference)
//
#include <hip/hip_runtime.h>

#define D0 128
#define D1 64
#define D2 32
#define DL 3

__device__ __forceinline__ float sigf(float x) {
    // sigmoid(x) = 1/(1+2^(-x*log2(e))); v_exp_f32 + v_rcp_f32, ~1 ulp
    float e = __builtin_amdgcn_exp2f(-1.44269504088896340736f * x);
    return __builtin_amdgcn_rcpf(1.0f + e);
}

// Lane-pair activation step.
// parity==0 lane holds the pre-activation a; parity==1 lane holds the tangent da.
// Both lanes run identical instructions (no divergence); pairing via DPP shuffle.
__device__ __forceinline__ float act_pair(float a, int parity) {
    float pe  = __shfl_xor(a, 1, 64);      // partner's accumulator
    float pre = parity ? pe : a;           // value-path pre-activation
    float sv  = sigf(pre);
    return parity ? sv * (1.0f - sv) * a   // dh = s'(a) * da
                  : sv;                    // h  = s(a)
}

// waves_per_eu pinned to exactly (4,4): LDS (36.9 KB/block) already caps us at
// 4 blocks/CU = 4 waves/SIMD, so targeting 8 waves (64 VGPRs) only buys spills.
// Pinning gives the allocator the full 128-VGPR budget -> a1[64] stays resident.
__attribute__((amdgpu_waves_per_eu(4, 4)))
__global__ __launch_bounds__(256) void sindy_fused(
    const float* __restrict__ x,  const float* __restrict__ dx,
    const float* __restrict__ W1, const float* __restrict__ b1,
    const float* __restrict__ W2, const float* __restrict__ b2,
    const float* __restrict__ W3, const float* __restrict__ b3,
    const float* __restrict__ V1, const float* __restrict__ c1,
    const float* __restrict__ V2, const float* __restrict__ c2,
    const float* __restrict__ V3, const float* __restrict__ c3,
    const float* __restrict__ Ew, const float* __restrict__ Eb,
    float* __restrict__ out, int n)
{
    const int tid    = threadIdx.x;
    const int parity = tid & 1;        // 0: value path (h), 1: tangent path (dh)
    const int half   = tid >> 7;       // staging group: 0 loads/stores x-side, 1 dx-side
    const int li     = tid & 127;
    const int s0     = blockIdx.x * 128;        // 128 samples per block
    const int samp   = s0 + (tid >> 1);         // this pair's sample

    // Row-per-thread staging tile. Row stride 36 dwords (144 B):
    // b128 ops get start-bank = (4*row + col) % 32 -> uniform over all 32 banks.
    __shared__ float st[256][36];

    // ---------------- encoder layer 1: 128 -> 64 ----------------
    float a1[D1];
    #pragma unroll
    for (int j = 0; j < D1; ++j) a1[j] = parity ? 0.0f : b1[j];

    const float* src = half ? dx : x;
    for (int c = 0; c < 4; ++c) {               // k-chunks of 32
        __syncthreads();
        #pragma unroll
        for (int q = 0; q < 8; ++q) {
            int idx4 = li + q * 128;            // 1024 float4 = 128 samples x 32 k
            int s  = idx4 >> 3;
            int kb = (idx4 & 7) * 4;
            float4 v = *(const float4*)(src + (size_t)(s0 + s) * D0 + c * 32 + kb);
            *(float4*)&st[2 * s + half][kb] = v;   // even rows: x, odd rows: dx
        }
        __syncthreads();
        #pragma unroll
        for (int kk = 0; kk < 32; kk += 4) {
            float4 xv = *(const float4*)&st[tid][kk];
            #pragma unroll
            for (int j = 0; j < D1; ++j) {
                const float* wr = W1 + j * D0 + c * 32 + kk;  // uniform -> s_load
                a1[j] = fmaf(wr[0], xv.x, a1[j]);
                a1[j] = fmaf(wr[1], xv.y, a1[j]);
                a1[j] = fmaf(wr[2], xv.z, a1[j]);
                a1[j] = fmaf(wr[3], xv.w, a1[j]);
            }
        }
    }
    #pragma unroll
    for (int j = 0; j < D1; ++j) a1[j] = act_pair(a1[j], parity);

    // ---------------- encoder layer 2: 64 -> 32 ----------------
    float a2[D2];
    #pragma unroll
    for (int j = 0; j < D2; ++j) {
        float a = parity ? 0.0f : b2[j];
        #pragma unroll
        for (int k = 0; k < D1; ++k) a = fmaf(W2[j * D1 + k], a1[k], a);
        a2[j] = act_pair(a, parity);
    }

    // ---------------- encoder layer 3: 32 -> 3 (linear) ----------------
    float zz[DL];
    #pragma unroll
    for (int j = 0; j < DL; ++j) {
        float a = parity ? 0.0f : b3[j];
        #pragma unroll
        for (int k = 0; k < D2; ++k) a = fmaf(W3[j * D2 + k], a2[k], a);
        zz[j] = a;                              // even: z, odd: dz
    }

    // ---------------- write z (even lanes) / dz (odd lanes) ----------------
    const size_t n3   = (size_t)n * 3;
    const size_t srow = (size_t)samp * 3;
    {
        float* zb = out + (parity ? n3 : 0);
        #pragma unroll
        for (int j = 0; j < DL; ++j) zb[srow + j] = zz[j];
    }

    // ---------------- SINDy library (22 terms) + dzb ----------------
    // Only even lanes' theta is meaningful; odd lanes compute harmless garbage.
    float th[22];
    th[0] = 1.0f; th[1] = 1.0f; th[2] = 1.0f;
    th[3] = zz[0]; th[4] = zz[1]; th[5] = zz[2];
    {
        int t = 6;
        #pragma unroll
        for (int i = 0; i < 3; ++i)
            #pragma unroll
            for (int j = i; j < 3; ++j) th[t++] = zz[i] * zz[j];
        #pragma unroll
        for (int i = 0; i < 3; ++i)
            #pragma unroll
            for (int j = i; j < 3; ++j)
                #pragma unroll
                for (int k = j; k < 3; ++k) th[t++] = zz[i] * zz[j] * zz[k];
    }
    float dzb[DL];
    #pragma unroll
    for (int j = 0; j < DL; ++j) {
        float a = Eb[j];
        #pragma unroll
        for (int q = 0; q < 22; ++q) a = fmaf(Ew[j * 22 + q], th[q], a);
        dzb[j] = a;
    }

    // decoder input per lane: even lanes use z, odd lanes need dzb (from partner)
    float qv[DL];
    #pragma unroll
    for (int k = 0; k < DL; ++k) {
        float t = __shfl_xor(dzb[k], 1, 64);
        qv[k] = parity ? t : zz[k];
    }
    if (!parity) {
        #pragma unroll
        for (int j = 0; j < DL; ++j) out[2 * n3 + srow + j] = dzb[j];
    }

    // ---------------- decoder layer 1: 3 -> 32 ----------------
    float g1[D2];
    #pragma unroll
    for (int j = 0; j < D2; ++j) {
        float a = parity ? 0.0f : c1[j];
        #pragma unroll
        for (int k = 0; k < DL; ++k) a = fmaf(V1[j * DL + k], qv[k], a);
        g1[j] = act_pair(a, parity);
    }

    // ---------------- decoder layer 2: 32 -> 64 ----------------
    float g2[D1];
    #pragma unroll
    for (int j = 0; j < D1; ++j) {
        float a = parity ? 0.0f : c2[j];
        #pragma unroll
        for (int k = 0; k < D2; ++k) a = fmaf(V2[j * D2 + k], g1[k], a);
        g2[j] = act_pair(a, parity);
    }

    // ---------------- decoder layer 3: 64 -> 128 (staged stores) ----------------
    float* oxb  = out + (size_t)n * 9;
    float* odxb = out + (size_t)n * 137;
    float* dstbase = half ? odxb : oxb;
    for (int jc = 0; jc < 8; ++jc) {
        float acc3[16];
        #pragma unroll
        for (int jj = 0; jj < 16; ++jj) {
            int j = jc * 16 + jj;
            float a = parity ? 0.0f : c3[j];
            #pragma unroll
            for (int k = 0; k < D1; ++k) a = fmaf(V3[j * D1 + k], g2[k], a);
            acc3[jj] = a;                       // even: xb chunk, odd: dxb chunk
        }
        __syncthreads();
        #pragma unroll
        for (int jj = 0; jj < 16; jj += 4) {
            float4 v;
            v.x = acc3[jj + 0]; v.y = acc3[jj + 1];
            v.z = acc3[jj + 2]; v.w = acc3[jj + 3];
            *(float4*)&st[tid][jj] = v;
        }
        __syncthreads();
        #pragma unroll
        for (int q = 0; q < 4; ++q) {
            int idx4 = li + q * 128;            // 512 float4 per output array
            int s  = idx4 >> 2;
            int jb = (idx4 & 3) * 4;
            float4 v = *(const float4*)&st[2 * s + half][jb];
            *(float4*)(dstbase + (size_t)(s0 + s) * D0 + jc * 16 + jb) = v;
        }
    }
}

extern "C" void kernel_launch(void* const* d_in, const int* in_sizes, int n_in,
                              void* d_out, int out_size, void* d_ws, size_t ws_size,
                              hipStream_t stream) {
    const float* x  = (const float*)d_in[0];
    const float* dx = (const float*)d_in[1];
    const float* W1 = (const float*)d_in[2];
    const float* b1 = (const float*)d_in[3];
    const float* W2 = (const float*)d_in[4];
    const float* b2 = (const float*)d_in[5];
    const float* W3 = (const float*)d_in[6];
    const float* b3 = (const float*)d_in[7];
    const float* V1 = (const float*)d_in[8];
    const float* c1 = (const float*)d_in[9];
    const float* V2 = (const float*)d_in[10];
    const float* c2 = (const float*)d_in[11];
    const float* V3 = (const float*)d_in[12];
    const float* c3 = (const float*)d_in[13];
    const float* Ew = (const float*)d_in[14];
    const float* Eb = (const float*)d_in[15];

    const int n = in_sizes[0] / D0;      // 262144
    const int grid = n / 128;            // 2048 blocks, 2 threads per sample

    sindy_fused<<<grid, 256, 0, stream>>>(x, dx, W1, b1, W2, b2, W3, b3,
                                          V1, c1, V2, c2, V3, c3, Ew, Eb,
                                          (float*)d_out, n);
}

// Round 3
// 2315.943 us; speedup vs baseline: 1.2607x; 1.2607x over previous
//
#include <hip/hip_runtime.h>

#define D0 128
#define D1 64
#define D2 32
#define DL 3

__device__ __forceinline__ float sigf(float x) {
    // sigmoid(x) = 1/(1+2^(-x*log2(e))); v_exp_f32 + v_rcp_f32, ~1 ulp
    float e = __builtin_amdgcn_exp2f(-1.44269504088896340736f * x);
    return __builtin_amdgcn_rcpf(1.0f + e);
}

// Lane-pair activation step.
// parity==0 lane holds the pre-activation a; parity==1 lane holds the tangent da.
__device__ __forceinline__ float act_pair(float a, int parity) {
    float pe  = __shfl_xor(a, 1, 64);      // partner's accumulator
    float pre = parity ? pe : a;           // value-path pre-activation
    float sv  = sigf(pre);
    return parity ? sv * (1.0f - sv) * a   // dh = s'(a) * da
                  : sv;                    // h  = s(a)
}

// LDS cap = 4 blocks/CU (36.9 KB each) -> 4 waves/SIMD; pin the budget to match.
// Peak live VGPRs is now ~105 (a1[64] + xv[32] + addr) since staging is DMA'd
// via global_load_lds (no data registers) -> fits 128, zero spill.
__attribute__((amdgpu_waves_per_eu(4, 4)))
__global__ __launch_bounds__(256) void sindy_fused(
    const float* __restrict__ x,  const float* __restrict__ dx,
    const float* __restrict__ W1, const float* __restrict__ b1,
    const float* __restrict__ W2, const float* __restrict__ b2,
    const float* __restrict__ W3, const float* __restrict__ b3,
    const float* __restrict__ V1, const float* __restrict__ c1,
    const float* __restrict__ V2, const float* __restrict__ c2,
    const float* __restrict__ V3, const float* __restrict__ c3,
    const float* __restrict__ Ew, const float* __restrict__ Eb,
    float* __restrict__ out, int n)
{
    const int tid    = threadIdx.x;
    const int parity = tid & 1;        // 0: value path (h), 1: tangent path (dh)
    const int p      = tid >> 1;       // pair index = local sample 0..127
    const int lane   = tid & 63;
    const int wv     = tid >> 6;       // wave 0..3
    const int half   = tid >> 7;       // dec3 store gather: 0 -> xb, 1 -> dxb
    const int li     = tid & 127;
    const int s0     = blockIdx.x * 128;        // 128 samples per block
    const int samp   = s0 + p;

    // 36 KB shared. enc1 staging view: first 32 KB = two [128 rows][8 float4]
    // regions (X then DX), columns XOR-swizzled by (row&7). dec3 view: [256][36].
    __shared__ float st[256][36];
    float* const stf = &st[0][0];

    // Swizzled source column for staging: lane l covers row (l>>3), slot (l&7);
    // slot c7 of row r must hold logical column c7 ^ (r&7); here r&7 == l>>3.
    const int colswz = (lane & 7) ^ (lane >> 3);

    // ---------------- encoder layer 1: 128 -> 64 ----------------
    float a1[D1];
    #pragma unroll
    for (int j = 0; j < D1; ++j) a1[j] = parity ? 0.0f : b1[j];

    for (int c = 0; c < 4; ++c) {               // k-chunks of 32
        __syncthreads();                        // prev chunk fully consumed
        {
            // waves 0,1 stage x rows 0..127; waves 2,3 stage dx rows 0..127
            const float* src  = (wv & 2) ? dx : x;
            const int   rbase = (wv & 1) * 64;
            const int   breg  = (wv >> 1) * 16384;      // X at 0, DX at 16 KB
            #pragma unroll
            for (int q = 0; q < 8; ++q) {
                int srow = rbase + q * 8 + (lane >> 3);
                const float* gp = src + (size_t)(s0 + srow) * D0 + c * 32 + colswz * 4;
                char* lp = (char*)stf + breg + (size_t)((wv & 1) * 8 + q) * 1024;
                __builtin_amdgcn_global_load_lds(
                    (const __attribute__((address_space(1))) void*)gp,
                    (__attribute__((address_space(3))) void*)lp,
                    16, 0, 0);                  // lane l -> lp + l*16 (linear)
            }
        }
        __syncthreads();                        // drains vmcnt before reads

        // even lanes read X row p, odd lanes read DX row p (swizzled slots)
        const float4* mrow = (const float4*)((const char*)stf + parity * 16384
                                             + (size_t)p * 128);
        float4 xv[8];
        #pragma unroll
        for (int f = 0; f < 8; ++f) xv[f] = mrow[f ^ (p & 7)];

        #pragma unroll
        for (int j = 0; j < D1; ++j) {
            const float* wr = W1 + j * D0 + c * 32;   // uniform -> s_load
            #pragma unroll
            for (int f = 0; f < 8; ++f) {
                a1[j] = fmaf(wr[f * 4 + 0], xv[f].x, a1[j]);
                a1[j] = fmaf(wr[f * 4 + 1], xv[f].y, a1[j]);
                a1[j] = fmaf(wr[f * 4 + 2], xv[f].z, a1[j]);
                a1[j] = fmaf(wr[f * 4 + 3], xv[f].w, a1[j]);
            }
        }
    }
    #pragma unroll
    for (int j = 0; j < D1; ++j) a1[j] = act_pair(a1[j], parity);

    // ---------------- encoder layer 2: 64 -> 32 ----------------
    float a2[D2];
    #pragma unroll
    for (int j = 0; j < D2; ++j) {
        float a = parity ? 0.0f : b2[j];
        #pragma unroll
        for (int k = 0; k < D1; ++k) a = fmaf(W2[j * D1 + k], a1[k], a);
        a2[j] = act_pair(a, parity);
    }

    // ---------------- encoder layer 3: 32 -> 3 (linear) ----------------
    float zz[DL];
    #pragma unroll
    for (int j = 0; j < DL; ++j) {
        float a = parity ? 0.0f : b3[j];
        #pragma unroll
        for (int k = 0; k < D2; ++k) a = fmaf(W3[j * D2 + k], a2[k], a);
        zz[j] = a;                              // even: z, odd: dz
    }

    // ---------------- write z (even lanes) / dz (odd lanes) ----------------
    const size_t n3   = (size_t)n * 3;
    const size_t srow = (size_t)samp * 3;
    {
        float* zb = out + (parity ? n3 : 0);
        #pragma unroll
        for (int j = 0; j < DL; ++j) zb[srow + j] = zz[j];
    }

    // ---------------- SINDy library (22 terms) + dzb ----------------
    // Only even lanes' theta is meaningful; odd lanes compute harmless garbage.
    float th[22];
    th[0] = 1.0f; th[1] = 1.0f; th[2] = 1.0f;
    th[3] = zz[0]; th[4] = zz[1]; th[5] = zz[2];
    {
        int t = 6;
        #pragma unroll
        for (int i = 0; i < 3; ++i)
            #pragma unroll
            for (int j = i; j < 3; ++j) th[t++] = zz[i] * zz[j];
        #pragma unroll
        for (int i = 0; i < 3; ++i)
            #pragma unroll
            for (int j = i; j < 3; ++j)
                #pragma unroll
                for (int k = j; k < 3; ++k) th[t++] = zz[i] * zz[j] * zz[k];
    }
    float dzb[DL];
    #pragma unroll
    for (int j = 0; j < DL; ++j) {
        float a = Eb[j];
        #pragma unroll
        for (int q = 0; q < 22; ++q) a = fmaf(Ew[j * 22 + q], th[q], a);
        dzb[j] = a;
    }

    // decoder input per lane: even lanes use z, odd lanes need dzb (from partner)
    float qv[DL];
    #pragma unroll
    for (int k = 0; k < DL; ++k) {
        float t = __shfl_xor(dzb[k], 1, 64);
        qv[k] = parity ? t : zz[k];
    }
    if (!parity) {
        #pragma unroll
        for (int j = 0; j < DL; ++j) out[2 * n3 + srow + j] = dzb[j];
    }

    // ---------------- decoder layer 1: 3 -> 32 ----------------
    float g1[D2];
    #pragma unroll
    for (int j = 0; j < D2; ++j) {
        float a = parity ? 0.0f : c1[j];
        #pragma unroll
        for (int k = 0; k < DL; ++k) a = fmaf(V1[j * DL + k], qv[k], a);
        g1[j] = act_pair(a, parity);
    }

    // ---------------- decoder layer 2: 32 -> 64 ----------------
    float g2[D1];
    #pragma unroll
    for (int j = 0; j < D1; ++j) {
        float a = parity ? 0.0f : c2[j];
        #pragma unroll
        for (int k = 0; k < D2; ++k) a = fmaf(V2[j * D2 + k], g1[k], a);
        g2[j] = act_pair(a, parity);
    }

    // ---------------- decoder layer 3: 64 -> 128 (staged stores) ----------------
    float* oxb  = out + (size_t)n * 9;
    float* odxb = out + (size_t)n * 137;
    float* dstbase = half ? odxb : oxb;
    for (int jc = 0; jc < 8; ++jc) {
        float acc3[16];
        #pragma unroll
        for (int jj = 0; jj < 16; ++jj) {
            int j = jc * 16 + jj;
            float a = parity ? 0.0f : c3[j];
            #pragma unroll
            for (int k = 0; k < D1; ++k) a = fmaf(V3[j * D1 + k], g2[k], a);
            acc3[jj] = a;                       // even: xb chunk, odd: dxb chunk
        }
        __syncthreads();
        #pragma unroll
        for (int jj = 0; jj < 16; jj += 4) {
            float4 v;
            v.x = acc3[jj + 0]; v.y = acc3[jj + 1];
            v.z = acc3[jj + 2]; v.w = acc3[jj + 3];
            *(float4*)&st[tid][jj] = v;
        }
        __syncthreads();
        #pragma unroll
        for (int q = 0; q < 4; ++q) {
            int idx4 = li + q * 128;            // 512 float4 per output array
            int s  = idx4 >> 2;
            int jb = (idx4 & 3) * 4;
            float4 v = *(const float4*)&st[2 * s + half][jb];
            *(float4*)(dstbase + (size_t)(s0 + s) * D0 + jc * 16 + jb) = v;
        }
    }
}

extern "C" void kernel_launch(void* const* d_in, const int* in_sizes, int n_in,
                              void* d_out, int out_size, void* d_ws, size_t ws_size,
                              hipStream_t stream) {
    const float* x  = (const float*)d_in[0];
    const float* dx = (const float*)d_in[1];
    const float* W1 = (const float*)d_in[2];
    const float* b1 = (const float*)d_in[3];
    const float* W2 = (const float*)d_in[4];
    const float* b2 = (const float*)d_in[5];
    const float* W3 = (const float*)d_in[6];
    const float* b3 = (const float*)d_in[7];
    const float* V1 = (const float*)d_in[8];
    const float* c1 = (const float*)d_in[9];
    const float* V2 = (const float*)d_in[10];
    const float* c2 = (const float*)d_in[11];
    const float* V3 = (const float*)d_in[12];
    const float* c3 = (const float*)d_in[13];
    const float* Ew = (const float*)d_in[14];
    const float* Eb = (const float*)d_in[15];

    const int n = in_sizes[0] / D0;      // 262144
    const int grid = n / 128;            // 2048 blocks, 2 threads per sample

    sindy_fused<<<grid, 256, 0, stream>>>(x, dx, W1, b1, W2, b2, W3, b3,
                                          V1, c1, V2, c2, V3, c3, Ew, Eb,
                                          (float*)d_out, n);
}

// Round 4
// 2049.764 us; speedup vs baseline: 1.4244x; 1.1299x over previous
//
#include <hip/hip_runtime.h>

#define D0 128
#define D1 64
#define D2 32
#define DL 3

__device__ __forceinline__ float sigf(float x) {
    // sigmoid(x) = 1/(1+2^(-x*log2(e))); v_exp_f32 + v_rcp_f32, ~1 ulp
    float e = __builtin_amdgcn_exp2f(-1.44269504088896340736f * x);
    return __builtin_amdgcn_rcpf(1.0f + e);
}

// Lane-pair activation step.
// parity==0 lane holds the pre-activation a; parity==1 lane holds the tangent da.
__device__ __forceinline__ float act_pair(float a, int parity) {
    float pe  = __shfl_xor(a, 1, 64);      // partner's accumulator
    float pre = parity ? pe : a;           // value-path pre-activation
    float sv  = sigf(pre);
    return parity ? sv * (1.0f - sv) * a   // dh = s'(a) * da
                  : sv;                    // h  = s(a)
}

// (256,2): the ONLY qualifier observed to unlock a >64-VGPR budget (R0: 112).
// Min 2 waves/EU -> allocator cap 256; true peak pressure ~90 -> no spill, and
// actual usage <=128 keeps 4 waves/SIMD, matching the LDS cap (36.9KB -> 4 blk/CU).
__global__ __launch_bounds__(256, 2) void sindy_fused(
    const float* __restrict__ x,  const float* __restrict__ dx,
    const float* __restrict__ W1, const float* __restrict__ b1,
    const float* __restrict__ W2, const float* __restrict__ b2,
    const float* __restrict__ W3, const float* __restrict__ b3,
    const float* __restrict__ V1, const float* __restrict__ c1,
    const float* __restrict__ V2, const float* __restrict__ c2,
    const float* __restrict__ V3, const float* __restrict__ c3,
    const float* __restrict__ Ew, const float* __restrict__ Eb,
    float* __restrict__ out, int n)
{
    const int tid    = threadIdx.x;
    const int parity = tid & 1;        // 0: value path (h), 1: tangent path (dh)
    const int p      = tid >> 1;       // pair index = local sample 0..127
    const int lane   = tid & 63;
    const int wv     = tid >> 6;       // wave 0..3
    const int half   = tid >> 7;       // dec3 store gather: 0 -> xb, 1 -> dxb
    const int li     = tid & 127;
    const int s0     = blockIdx.x * 128;        // 128 samples per block
    const int samp   = s0 + p;

    // 36 KB shared. enc1 staging view: first 32 KB = two [128 rows][8 float4]
    // regions (X then DX), columns XOR-swizzled by (row&7). dec3 view: [256][36].
    __shared__ float st[256][36];
    float* const stf = &st[0][0];

    // Swizzled source column for staging: lane l covers row (l>>3), slot (l&7);
    // slot c7 of row r must hold logical column c7 ^ (r&7); here r&7 == l>>3.
    const int colswz = (lane & 7) ^ (lane >> 3);

    // ---------------- encoder layer 1: 128 -> 64 ----------------
    float a1[D1];
    #pragma unroll
    for (int j = 0; j < D1; ++j) a1[j] = parity ? 0.0f : b1[j];

    for (int c = 0; c < 4; ++c) {               // k-chunks of 32
        __syncthreads();                        // prev chunk fully consumed
        {
            // waves 0,1 stage x rows 0..127; waves 2,3 stage dx rows 0..127
            const float* src  = (wv & 2) ? dx : x;
            const int   rbase = (wv & 1) * 64;
            const int   breg  = (wv >> 1) * 16384;      // X at 0, DX at 16 KB
            #pragma unroll
            for (int q = 0; q < 8; ++q) {
                int srow = rbase + q * 8 + (lane >> 3);
                const float* gp = src + (size_t)(s0 + srow) * D0 + c * 32 + colswz * 4;
                char* lp = (char*)stf + breg + (size_t)((wv & 1) * 8 + q) * 1024;
                __builtin_amdgcn_global_load_lds(
                    (const __attribute__((address_space(1))) void*)gp,
                    (__attribute__((address_space(3))) void*)lp,
                    16, 0, 0);                  // lane l -> lp + l*16 (linear)
            }
        }
        __syncthreads();                        // drains vmcnt before reads

        // even lanes read X row p, odd lanes read DX row p (swizzled slots).
        // Two half-groups of 4 float4 -> only 16 transient VGPRs live at once.
        const float4* mrow = (const float4*)((const char*)stf + parity * 16384
                                             + (size_t)p * 128);
        #pragma unroll
        for (int hk = 0; hk < 2; ++hk) {
            float4 xv[4];
            #pragma unroll
            for (int f = 0; f < 4; ++f) xv[f] = mrow[(hk * 4 + f) ^ (p & 7)];
            #pragma unroll
            for (int j = 0; j < D1; ++j) {
                const float* wr = W1 + j * D0 + c * 32 + hk * 16;  // uniform -> s_load
                #pragma unroll
                for (int f = 0; f < 4; ++f) {
                    a1[j] = fmaf(wr[f * 4 + 0], xv[f].x, a1[j]);
                    a1[j] = fmaf(wr[f * 4 + 1], xv[f].y, a1[j]);
                    a1[j] = fmaf(wr[f * 4 + 2], xv[f].z, a1[j]);
                    a1[j] = fmaf(wr[f * 4 + 3], xv[f].w, a1[j]);
                }
            }
        }
    }
    #pragma unroll
    for (int j = 0; j < D1; ++j) a1[j] = act_pair(a1[j], parity);

    // ---------------- encoder layer 2: 64 -> 32 ----------------
    float a2[D2];
    #pragma unroll
    for (int j = 0; j < D2; ++j) {
        float a = parity ? 0.0f : b2[j];
        #pragma unroll
        for (int k = 0; k < D1; ++k) a = fmaf(W2[j * D1 + k], a1[k], a);
        a2[j] = act_pair(a, parity);
    }

    // ---------------- encoder layer 3: 32 -> 3 (linear) ----------------
    float zz[DL];
    #pragma unroll
    for (int j = 0; j < DL; ++j) {
        float a = parity ? 0.0f : b3[j];
        #pragma unroll
        for (int k = 0; k < D2; ++k) a = fmaf(W3[j * D2 + k], a2[k], a);
        zz[j] = a;                              // even: z, odd: dz
    }

    // ---------------- write z (even lanes) / dz (odd lanes) ----------------
    const size_t n3   = (size_t)n * 3;
    const size_t srow = (size_t)samp * 3;
    {
        float* zb = out + (parity ? n3 : 0);
        #pragma unroll
        for (int j = 0; j < DL; ++j) zb[srow + j] = zz[j];
    }

    // ---------------- SINDy library (22 terms) + dzb ----------------
    // Only even lanes' theta is meaningful; odd lanes compute harmless garbage.
    float th[22];
    th[0] = 1.0f; th[1] = 1.0f; th[2] = 1.0f;
    th[3] = zz[0]; th[4] = zz[1]; th[5] = zz[2];
    {
        int t = 6;
        #pragma unroll
        for (int i = 0; i < 3; ++i)
            #pragma unroll
            for (int j = i; j < 3; ++j) th[t++] = zz[i] * zz[j];
        #pragma unroll
        for (int i = 0; i < 3; ++i)
            #pragma unroll
            for (int j = i; j < 3; ++j)
                #pragma unroll
                for (int k = j; k < 3; ++k) th[t++] = zz[i] * zz[j] * zz[k];
    }
    float dzb[DL];
    #pragma unroll
    for (int j = 0; j < DL; ++j) {
        float a = Eb[j];
        #pragma unroll
        for (int q = 0; q < 22; ++q) a = fmaf(Ew[j * 22 + q], th[q], a);
        dzb[j] = a;
    }

    // decoder input per lane: even lanes use z, odd lanes need dzb (from partner)
    float qv[DL];
    #pragma unroll
    for (int k = 0; k < DL; ++k) {
        float t = __shfl_xor(dzb[k], 1, 64);
        qv[k] = parity ? t : zz[k];
    }
    if (!parity) {
        #pragma unroll
        for (int j = 0; j < DL; ++j) out[2 * n3 + srow + j] = dzb[j];
    }

    // ---------------- decoder layer 1: 3 -> 32 ----------------
    float g1[D2];
    #pragma unroll
    for (int j = 0; j < D2; ++j) {
        float a = parity ? 0.0f : c1[j];
        #pragma unroll
        for (int k = 0; k < DL; ++k) a = fmaf(V1[j * DL + k], qv[k], a);
        g1[j] = act_pair(a, parity);
    }

    // ---------------- decoder layer 2: 32 -> 64 ----------------
    float g2[D1];
    #pragma unroll
    for (int j = 0; j < D1; ++j) {
        float a = parity ? 0.0f : c2[j];
        #pragma unroll
        for (int k = 0; k < D2; ++k) a = fmaf(V2[j * D2 + k], g1[k], a);
        g2[j] = act_pair(a, parity);
    }

    // ---------------- decoder layer 3: 64 -> 128 (staged stores) ----------------
    float* oxb  = out + (size_t)n * 9;
    float* odxb = out + (size_t)n * 137;
    float* dstbase = half ? odxb : oxb;
    for (int jc = 0; jc < 8; ++jc) {
        float acc3[16];
        #pragma unroll
        for (int jj = 0; jj < 16; ++jj) {
            int j = jc * 16 + jj;
            float a = parity ? 0.0f : c3[j];
            #pragma unroll
            for (int k = 0; k < D1; ++k) a = fmaf(V3[j * D1 + k], g2[k], a);
            acc3[jj] = a;                       // even: xb chunk, odd: dxb chunk
        }
        __syncthreads();
        #pragma unroll
        for (int jj = 0; jj < 16; jj += 4) {
            float4 v;
            v.x = acc3[jj + 0]; v.y = acc3[jj + 1];
            v.z = acc3[jj + 2]; v.w = acc3[jj + 3];
            *(float4*)&st[tid][jj] = v;
        }
        __syncthreads();
        #pragma unroll
        for (int q = 0; q < 4; ++q) {
            int idx4 = li + q * 128;            // 512 float4 per output array
            int s  = idx4 >> 2;
            int jb = (idx4 & 3) * 4;
            float4 v = *(const float4*)&st[2 * s + half][jb];
            *(float4*)(dstbase + (size_t)(s0 + s) * D0 + jc * 16 + jb) = v;
        }
    }
}

extern "C" void kernel_launch(void* const* d_in, const int* in_sizes, int n_in,
                              void* d_out, int out_size, void* d_ws, size_t ws_size,
                              hipStream_t stream) {
    const float* x  = (const float*)d_in[0];
    const float* dx = (const float*)d_in[1];
    const float* W1 = (const float*)d_in[2];
    const float* b1 = (const float*)d_in[3];
    const float* W2 = (const float*)d_in[4];
    const float* b2 = (const float*)d_in[5];
    const float* W3 = (const float*)d_in[6];
    const float* b3 = (const float*)d_in[7];
    const float* V1 = (const float*)d_in[8];
    const float* c1 = (const float*)d_in[9];
    const float* V2 = (const float*)d_in[10];
    const float* c2 = (const float*)d_in[11];
    const float* V3 = (const float*)d_in[12];
    const float* c3 = (const float*)d_in[13];
    const float* Ew = (const float*)d_in[14];
    const float* Eb = (const float*)d_in[15];

    const int n = in_sizes[0] / D0;      // 262144
    const int grid = n / 128;            // 2048 blocks, 2 threads per sample

    sindy_fused<<<grid, 256, 0, stream>>>(x, dx, W1, b1, W2, b2, W3, b3,
                                          V1, c1, V2, c2, V3, c3, Ew, Eb,
                                          (float*)d_out, n);
}